// Round 7
// baseline (210.137 us; speedup 1.0000x reference)
//
#include <hip/hip_runtime.h>

#define HW 224
#define NIMG 64
#define RB 10                           // patch-row-band height (assignment window)
#define RSTG 20                         // staged rows = RB + max halo (K-1 = 10)
#define NBAND 23                        // ceil(224/10)
#define NGROUP 960                      // 64 * 3 * 5
#define ACC_STRIDE 128                  // per-group ints: bins 0..123, sums 124..126

// histogram sub-offsets per kidx (sizes KK+1: 10,26,50,82,122 -> total 290)
#define HTOT 290
__device__ __constant__ int HOFF[5] = {0, 10, 36, 86, 168};

// ---------------- 128-bit bitmask helpers (registers only) -----------------
struct U128 { unsigned long long lo, hi; };
__device__ __forceinline__ U128 u_or  (U128 a, U128 b){ return {a.lo|b.lo, a.hi|b.hi}; }
__device__ __forceinline__ U128 u_and (U128 a, U128 b){ return {a.lo&b.lo, a.hi&b.hi}; }
__device__ __forceinline__ U128 u_andn(U128 a, U128 b){ return {a.lo&~b.lo, a.hi&~b.hi}; }
__device__ __forceinline__ bool u_eq(U128 a, U128 b){ return a.lo==b.lo && a.hi==b.hi; }
__device__ __forceinline__ bool u_nz(U128 a){ return (a.lo | a.hi) != 0ull; }
__device__ __forceinline__ U128 u_shl(U128 a, int n){           // 1 <= n < 64
    return { a.lo << n, (a.hi << n) | (a.lo >> (64 - n)) };
}
__device__ __forceinline__ U128 u_shr(U128 a, int n){
    return { (a.lo >> n) | (a.hi << (64 - n)), a.hi >> n };
}
__device__ __forceinline__ int u_pop(U128 a){ return __popcll(a.lo) + __popcll(a.hi); }
__device__ __forceinline__ U128 u_low(U128 a){
    if (a.lo) return { a.lo & (0ull - a.lo), 0ull };
    return { 0ull, a.hi & (0ull - a.hi) };
}

// ---------------- per-K band compute ---------------------------------------
// LDS layout: RSTG rows, stride 232 floats; image col c at LDS col 4+c;
// LDS cols 0..3 and 228..231 zeroed; rows beyond image zeroed.
// Patch-row r (start row s=r*K-PAD) is assigned to this band iff
// max(s,0) in [y0, y0+RB). Needed rows are then within the staged window
// (top-pad rows s<0 handled via the constant-zero path, K=11 band 0 only).

template<int K>
__device__ __forceinline__ void band_k(const float* __restrict__ ldsf, int y0,
                                       int kidx, int (*hist)[HTOT], int* sums) {
    constexpr int KK   = K * K;
    constexpr int ROWS = (HW + K - 1) / K;
    constexpr int PAD  = (ROWS * K - HW) / 2;        // 0 except K=11 -> 3
    const int hoff = HOFF[kidx];
    const int wid = (threadIdx.x >> 7) & 1;

    int rlo = (y0 == 0) ? 0 : (y0 + PAD + K - 1) / K;
    int rhi = (y0 + RB + PAD + K - 1) / K;
    if (rhi > ROWS) rhi = ROWS;
    if (rhi <= rlo) return;                          // block-uniform
    const int cnt = (rhi - rlo) * ROWS;

    int t_perc = 0, t_ncomp = 0, t_marea = 0;

    for (int t = threadIdx.x; t < cnt; t += 256) {
        const int pr = rlo + t / ROWS, pc = t - (t / ROWS) * ROWS;
        const int gr0  = pr * K - PAD - y0;          // lds row of patch row 0 (>= -3)
        const int base = pc * K + (4 - PAD);         // lds col of patch col 0
        const float cen = ldsf[(gr0 + K / 2) * 232 + base + K / 2];

        int ones, ncomp = 0, maxsz = 0;

        if constexpr (KK <= 64) {
            unsigned long long LCOL = 0ull, RCOL = 0ull;
#pragma unroll
            for (int i = 0; i < K; i++) { LCOL |= 1ull << (i*K); RCOL |= 1ull << (i*K + K - 1); }
            unsigned long long msk = 0ull;
#pragma unroll
            for (int i = 0; i < K; i++) {
                const int rb2 = (gr0 + i) * 232 + base;
#pragma unroll
                for (int j = 0; j < K; j++) {
                    const float v = ldsf[rb2 + j];
                    msk |= (fabsf(v - cen) <= (float)K ? 1ull : 0ull) << (i * K + j);
                }
            }
            ones = __popcll(msk);
            unsigned long long m = msk;
            while (m) {
                unsigned long long s = m & (0ull - m);
                for (;;) {
                    unsigned long long g = s | ((s & ~RCOL) << 1) | ((s & ~LCOL) >> 1)
                                             | (s << K) | (s >> K);
                    g &= m;
                    if (g == s) break;
                    s = g;
                }
                ncomp++;
                const int sz = __popcll(s);
                if (sz > maxsz) maxsz = sz;
                m &= ~s;
            }
        } else {
            U128 LCOL{0,0}, RCOL{0,0};
#pragma unroll
            for (int i = 0; i < K; i++) {
                const int cl = i * K, cr = i * K + K - 1;
                if (cl < 64) LCOL.lo |= 1ull << cl; else LCOL.hi |= 1ull << (cl - 64);
                if (cr < 64) RCOL.lo |= 1ull << cr; else RCOL.hi |= 1ull << (cr - 64);
            }
            U128 msk{0, 0};
#pragma unroll
            for (int i = 0; i < K; i++) {
                bool padrow = false;
                if constexpr (PAD > 0) padrow = (gr0 + i < 0);   // top zero-pad rows
                if (padrow) {
                    if (cen <= (float)K) {                       // |0-cen| <= K
                        const int c0 = i * K;                    // i<3 -> bits in lo
                        msk.lo |= (((1ull << K) - 1ull) << c0);
                    }
                } else {
                    const int rb2 = (gr0 + i) * 232 + base;
#pragma unroll
                    for (int j = 0; j < K; j++) {
                        const float v = ldsf[rb2 + j];
                        const unsigned long long bit = (fabsf(v - cen) <= (float)K) ? 1ull : 0ull;
                        const int c = i * K + j;
                        if (c < 64) msk.lo |= bit << c; else msk.hi |= bit << (c - 64);
                    }
                }
            }
            ones = u_pop(msk);
            U128 m = msk;
            while (u_nz(m)) {
                U128 s = u_low(m);
                for (;;) {
                    U128 g = s;
                    g = u_or(g, u_shl(u_andn(s, RCOL), 1));
                    g = u_or(g, u_shr(u_andn(s, LCOL), 1));
                    g = u_or(g, u_shl(s, K));
                    g = u_or(g, u_shr(s, K));
                    g = u_and(g, m);
                    if (u_eq(g, s)) break;
                    s = g;
                }
                ncomp++;
                const int sz = u_pop(s);
                if (sz > maxsz) maxsz = sz;
                m = u_andn(m, s);
            }
        }

        const int bgcnt = KK - ones;                 // background label 0 count
        const int marea = (bgcnt > maxsz) ? bgcnt : maxsz;
        t_ncomp += ncomp;
        t_marea += marea;
        if ((float)ones / (float)KK >= 0.59275f) t_perc++;
        atomicAdd(&hist[wid][hoff + ones], 1);
    }

    // wave-reduce partial sums, one atomic per wave
#pragma unroll
    for (int off = 32; off; off >>= 1) {
        t_perc  += __shfl_down(t_perc,  off, 64);
        t_ncomp += __shfl_down(t_ncomp, off, 64);
        t_marea += __shfl_down(t_marea, off, 64);
    }
    if ((threadIdx.x & 63) == 0) {
        atomicAdd(&sums[kidx * 3 + 0], t_perc);
        atomicAdd(&sums[kidx * 3 + 1], t_ncomp);
        atomicAdd(&sums[kidx * 3 + 2], t_marea);
    }
}

// ---------------- stage-1 kernel: one block per (image, ch, band) ----------
// grid = 64*3*23 = 4416; XCD swizzle keeps one image's blocks on one XCD.

__global__ __launch_bounds__(256) void fractal_stats(const float* __restrict__ in,
                                                     int* __restrict__ gacc) {
    const int xcd  = blockIdx.x & 7;
    const int slot = blockIdx.x >> 3;                // 0..551
    const int b    = xcd + 8 * (slot / 69);          // image on XCD b%8
    const int t2   = slot % 69;                      // 69 = 3 * NBAND
    const int ch   = t2 / NBAND;
    const int band = t2 % NBAND;
    const int y0   = band * RB;
    const int tid  = threadIdx.x;

    __shared__ float4 lds4[RSTG * 58];               // 18,560 B
    __shared__ int hist[2][HTOT];                    // 2,320 B
    __shared__ int sums[15];

    for (int i = tid; i < 2 * HTOT; i += 256) ((int*)hist)[i] = 0;
    if (tid < 15) sums[tid] = 0;

    // ---- staging: float4-coalesced from NHWC, extract block-uniform channel
    const float* imgbase = in + (size_t)b * HW * HW * 3;
    for (int i = tid; i < RSTG * 56; i += 256) {
        const int r = i / 56, t4 = i - r * 56;
        const int gy = y0 + r;
        float4 v = {0.f, 0.f, 0.f, 0.f};
        if (gy < HW) {                               // 16B aligned: 12*(gy*56+t4)*4B
            const float4* s4 = (const float4*)(imgbase + 3 * (gy * HW + 4 * t4));
            const float4 A = s4[0], B = s4[1], C = s4[2];
            if (ch == 0)      v = float4{A.x, A.w, B.z, C.y};
            else if (ch == 1) v = float4{A.y, B.x, B.w, C.z};
            else              v = float4{A.z, B.y, C.x, C.w};
        }
        lds4[r * 58 + 1 + t4] = v;
    }
    for (int i = tid; i < RSTG * 2; i += 256) {      // zero pad cols 0..3 / 228..231
        const int r = i >> 1, w = i & 1;
        lds4[r * 58 + (w ? 57 : 0)] = float4{0.f, 0.f, 0.f, 0.f};
    }
    __syncthreads();

    const float* ldsf = (const float*)lds4;
    band_k<3 >(ldsf, y0, 0, hist, sums);
    band_k<5 >(ldsf, y0, 1, hist, sums);
    band_k<7 >(ldsf, y0, 2, hist, sums);
    band_k<9 >(ldsf, y0, 3, hist, sums);
    band_k<11>(ldsf, y0, 4, hist, sums);
    __syncthreads();

    // ---- sparse global accumulation into per-group accumulators ----
    const int gbase = ((b * 3 + ch) * 5) * ACC_STRIDE;
    for (int t = tid; t < 300; t += 256) {
        if (t < 285) {                               // useful bins: 9+25+49+81+121
            int kidx, bin;
            if      (t < 9)   { kidx = 0; bin = t; }
            else if (t < 34)  { kidx = 1; bin = t - 9; }
            else if (t < 83)  { kidx = 2; bin = t - 34; }
            else if (t < 164) { kidx = 3; bin = t - 83; }
            else              { kidx = 4; bin = t - 164; }
            const int v = hist[0][HOFF[kidx] + bin] + hist[1][HOFF[kidx] + bin];
            if (v) atomicAdd(&gacc[gbase + kidx * ACC_STRIDE + bin], v);
        } else {
            const int q = t - 285, kidx = q / 3, m = q - 3 * kidx;
            const int v = sums[kidx * 3 + m];
            if (v) atomicAdd(&gacc[gbase + kidx * ACC_STRIDE + 124 + m], v);
        }
    }
}

// ---------------- zero accumulators ----------------------------------------
__global__ __launch_bounds__(256) void zero_accum(int* __restrict__ gacc) {
    const int tid = blockIdx.x * 256 + threadIdx.x;
    if (tid < NGROUP * ACC_STRIDE) gacc[tid] = 0;
}

// ---------------- finalize: metrics per group ------------------------------
__global__ __launch_bounds__(256) void fractal_finalize(const int* __restrict__ gacc,
                                                        float* __restrict__ interm) {
    const int g = blockIdx.x * 256 + threadIdx.x;
    if (g >= NGROUP) return;                         // g = (b*3+ch)*5 + kidx
    const int kidx = g % 5;
    const int t = g / 5, ch = t % 3, b = t / 3;
    const int k = 3 + 2 * kidx, kk = k * k;
    const int rows = (HW + k - 1) / k;
    const int P = rows * rows;
    const int* acc = gacc + g * ACC_STRIDE;

    float fd = 0.0f, m1 = 0.0f, m2 = 0.0f;
    const float Pf = (float)P;
    for (int s = 0; s < kk; s++) {                   // bin kk excluded (ref drops it)
        const float prob = (float)acc[s] / Pf;
        const float n = (float)(s + 1);
        fd += prob / n;
        m1 += prob * n;
        m2 += prob * prob * n;
    }
    const float lac = (m2 - m1 * m1) / (m1 * m1);
    float* o = interm + (size_t)b * 75 + kidx * 3 + ch;
    o[0]  = (float)(acc[125] / P);   // acn  (integer floor mean)
    o[15] = (float)(acc[124] / P);   // acp
    o[30] = (float)(acc[126] / P);   // acma
    o[45] = lac;
    o[60] = fd;
}

// ---------------- stage 2: 5x5 -> 224x224 bilinear (jax half-pixel) --------
__global__ __launch_bounds__(256) void fractal_resize(const float* __restrict__ interm,
                                                      float* __restrict__ out, int total) {
    const int idx = blockIdx.x * 256 + threadIdx.x;
    if (idx >= total) return;
    const int ch = idx % 3;
    int t = idx / 3;
    const int x = t % HW; t /= HW;
    const int y = t % HW;
    const int b = t / HW;

    const float sc = 5.0f / 224.0f;
    const float uy = ((float)y + 0.5f) * sc - 0.5f;   // in (-0.5, 4.5)
    const float ux = ((float)x + 0.5f) * sc - 0.5f;

    const float fy = floorf(uy), fx = floorf(ux);
    const float wy = uy - fy,    wx = ux - fx;
    int y0 = (int)fy, x0 = (int)fx;
    int y1 = y0 + 1,  x1 = x0 + 1;
    if (y0 < 0) y0 = 0; if (x0 < 0) x0 = 0;
    if (y1 > 4) y1 = 4; if (x1 > 4) x1 = 4;

    const float* g = interm + (size_t)b * 75 + ch;
    const float v00 = g[(y0 * 5 + x0) * 3];
    const float v01 = g[(y0 * 5 + x1) * 3];
    const float v10 = g[(y1 * 5 + x0) * 3];
    const float v11 = g[(y1 * 5 + x1) * 3];

    out[idx] = (1.0f - wy) * ((1.0f - wx) * v00 + wx * v01)
             +         wy  * ((1.0f - wx) * v10 + wx * v11);
}

// ---------------- launcher -------------------------------------------------
extern "C" void kernel_launch(void* const* d_in, const int* in_sizes, int n_in,
                              void* d_out, int out_size, void* d_ws, size_t ws_size,
                              hipStream_t stream) {
    const float* in = (const float*)d_in[0];
    float* out = (float*)d_out;
    float* interm = (float*)d_ws;                    // 19,200 B
    int*   gacc   = (int*)((char*)d_ws + 19456);     // 491,520 B

    zero_accum<<<(NGROUP * ACC_STRIDE + 255) / 256, 256, 0, stream>>>(gacc);
    fractal_stats<<<NIMG * 3 * NBAND, 256, 0, stream>>>(in, gacc);
    fractal_finalize<<<(NGROUP + 255) / 256, 256, 0, stream>>>(gacc, interm);
    fractal_resize<<<(out_size + 255) / 256, 256, 0, stream>>>(interm, out, out_size);
}